// Round 1
// baseline (469.190 us; speedup 1.0000x reference)
//
#include <hip/hip_runtime.h>

#define TT 128
#define DD 64
#define BHN 32
#define SCALE 0.125f
#define NEGF -1000000.0f

// float-element offsets into d_out (concatenated return order: z, pre, vg, M, L)
#define OFF_Z   ((size_t)0)
#define OFF_PRE ((size_t)(BHN*TT*DD))                       // 262144
#define OFF_VG  (OFF_PRE + (size_t)BHN*TT*TT*TT)            // 67371008
#define OFF_M   (OFF_VG + (size_t)BHN*TT*TT*DD)             // 100925440
#define OFF_L   (OFF_M + (size_t)(BHN*TT))                  // 100929536

// ---------------- v_gated: vg[bn, p, t, h] = silu(v1[p,h]) * v2[t,h] ----------------
__global__ __launch_bounds__(256) void k_vg(const float* __restrict__ v1,
                                            const float* __restrict__ v2,
                                            float* __restrict__ out) {
    const int bid = blockIdx.x;      // bn*128 + p
    const int bn  = bid >> 7;
    const int p   = bid & 127;
    const int tid = threadIdx.x;
    __shared__ float g1[DD];
    if (tid < DD) {
        float x = v1[(size_t)(bn*TT + p)*DD + tid];
        g1[tid] = x / (1.0f + __expf(-x));
    }
    __syncthreads();
    const float4* v2f = (const float4*)(v2 + (size_t)bn*TT*DD);
    float4* dst = (float4*)(out + OFF_VG + (size_t)bid*TT*DD);
    const float4* g14 = (const float4*)g1;
    for (int i = tid; i < TT*DD/4; i += 256) {
        int h4 = i & 15;
        float4 v = v2f[i];
        float4 g = g14[h4];
        float4 r;
        r.x = v.x * g.x; r.y = v.y * g.y; r.z = v.z * g.z; r.w = v.w * g.w;
        dst[i] = r;
    }
}

// ---------------- pre_softmax: per (bn, j) block, s[k,q] = sum_h k1[j,h]*k2[k,h]*q[q,h] ----------------
__global__ __launch_bounds__(256) void k_score(const float* __restrict__ q,
                                               const float* __restrict__ k1,
                                               const float* __restrict__ k2,
                                               float* __restrict__ out) {
    const int bid = blockIdx.x;      // bn*128 + j
    const int bn  = bid >> 7;
    const int j   = bid & 127;
    const int tid = threadIdx.x;
    __shared__ float shW[DD][132];   // w[h][k] = k1[j,h]*k2[k,h]  (pad 132 for transpose-write banks)
    __shared__ float shQ[DD][132];   // q[h][qq]
    const float* k1r = k1 + (size_t)bid*DD;
    const float* k2t = k2 + (size_t)bn*TT*DD;
    const float* qt  = q  + (size_t)bn*TT*DD;
    for (int e = tid; e < TT*DD; e += 256) {
        int r = e >> 6;
        int h = e & 63;
        float k1v = __ldg(k1r + h);
        shW[h][r] = k1v * k2t[e];
        shQ[h][r] = qt[e];
    }
    __syncthreads();
    const int q0 = (tid & 15) * 8;
    const int k0 = (tid >> 4) * 8;
    float acc[8][8];
#pragma unroll
    for (int a = 0; a < 8; a++)
#pragma unroll
        for (int b = 0; b < 8; b++) acc[a][b] = 0.f;
#pragma unroll 4
    for (int h = 0; h < DD; h++) {
        float wv[8], qv[8];
#pragma unroll
        for (int a = 0; a < 8; a++) wv[a] = shW[h][k0 + a];
#pragma unroll
        for (int b = 0; b < 8; b++) qv[b] = shQ[h][q0 + b];
#pragma unroll
        for (int a = 0; a < 8; a++)
#pragma unroll
            for (int b = 0; b < 8; b++)
                acc[a][b] = fmaf(wv[a], qv[b], acc[a][b]);
    }
    float* dst = out + OFF_PRE + (size_t)bid*TT*TT;   // [k][q] tile, q innermost
#pragma unroll
    for (int a = 0; a < 8; a++) {
        const int k = k0 + a;
        float row[8];
#pragma unroll
        for (int b = 0; b < 8; b++) {
            int qi = q0 + b;
            row[b] = ((j <= qi) && (k <= qi)) ? acc[a][b] : NEGF;
        }
        float4* p = (float4*)(dst + (size_t)k*TT + q0);
        p[0] = make_float4(row[0], row[1], row[2], row[3]);
        p[1] = make_float4(row[4], row[5], row[6], row[7]);
    }
}

// ---------------- z, M, L: per (bn, q) block ----------------
__global__ __launch_bounds__(256) void k_z(const float* __restrict__ q,
                                           const float* __restrict__ k1,
                                           const float* __restrict__ k2,
                                           const float* __restrict__ v1,
                                           const float* __restrict__ v2,
                                           float* __restrict__ out) {
    const int bid = blockIdx.x;      // bn*128 + qq
    const int bn  = bid >> 7;
    const int qq  = bid & 127;
    const int tid = threadIdx.x;

    __shared__ float shBuf[2*DD*132];     // phase1: shA[64][132] + shK2[64][132]; phase2 union: attnT[128][128]
    __shared__ float shG2[TT][DD];        // v2[k][h]
    __shared__ float shZ[16][DD];
    __shared__ float scrMax[4];
    __shared__ float scrSum[4];

    float (*shA)[132]  = (float(*)[132])shBuf;
    float (*shK2)[132] = (float(*)[132])(shBuf + DD*132);
    float (*attnT)[TT] = (float(*)[TT])shBuf;

    const float* qrow = q  + (size_t)bid*DD;
    const float* k1t  = k1 + (size_t)bn*TT*DD;
    const float* k2t  = k2 + (size_t)bn*TT*DD;
    const float* v2t  = v2 + (size_t)bn*TT*DD;

    for (int e = tid; e < TT*DD; e += 256) {
        int r = e >> 6;
        int h = e & 63;
        float qv = __ldg(qrow + h);
        shA[h][r]  = k1t[e] * qv;       // a[h][j] = k1[j,h]*q[qq,h]
        shK2[h][r] = k2t[e];            // k2[h][k]
        ((float*)shG2)[e] = v2t[e];     // g2[k][h] row-major
    }
    __syncthreads();

    // phase 1 GEMM: s[j,k] = sum_h a[h][j]*k2[h][k]
    const int j0 = (tid & 15) * 8;
    const int k0 = (tid >> 4) * 8;
    float acc[8][8];
#pragma unroll
    for (int a = 0; a < 8; a++)
#pragma unroll
        for (int b = 0; b < 8; b++) acc[a][b] = 0.f;
#pragma unroll 4
    for (int h = 0; h < DD; h++) {
        float av[8], bv[8];
#pragma unroll
        for (int a = 0; a < 8; a++) av[a] = shA[h][j0 + a];
#pragma unroll
        for (int b = 0; b < 8; b++) bv[b] = shK2[h][k0 + b];
#pragma unroll
        for (int a = 0; a < 8; a++)
#pragma unroll
            for (int b = 0; b < 8; b++)
                acc[a][b] = fmaf(av[a], bv[b], acc[a][b]);
    }

    // mask + scale; thread max
    float m = -3.4e38f;
#pragma unroll
    for (int a = 0; a < 8; a++)
#pragma unroll
        for (int b = 0; b < 8; b++) {
            bool valid = ((j0 + a) <= qq) && ((k0 + b) <= qq);
            float sv = valid ? acc[a][b] * SCALE : (NEGF * SCALE);
            acc[a][b] = sv;
            m = fmaxf(m, sv);
        }
#pragma unroll
    for (int o = 32; o >= 1; o >>= 1) m = fmaxf(m, __shfl_xor(m, o));
    if ((tid & 63) == 0) scrMax[tid >> 6] = m;
    __syncthreads();                                      // also: all reads of shA/shK2 done
    const float M = fmaxf(fmaxf(scrMax[0], scrMax[1]), fmaxf(scrMax[2], scrMax[3]));

    // P = exp(scaled - M); masked underflows to exactly 0 (matches fp32 ref)
    float ssum = 0.f;
#pragma unroll
    for (int a = 0; a < 8; a++)
#pragma unroll
        for (int b = 0; b < 8; b++) {
            float p = __expf(acc[a][b] - M);
            acc[a][b] = p;
            ssum += p;
        }
#pragma unroll
    for (int o = 32; o >= 1; o >>= 1) ssum += __shfl_xor(ssum, o);
    if ((tid & 63) == 0) scrSum[tid >> 6] = ssum;

    // stage P transposed into LDS (overwrites shA/shK2 region)
#pragma unroll
    for (int b = 0; b < 8; b++) {
        float4* p = (float4*)(&attnT[k0 + b][j0]);
        p[0] = make_float4(acc[0][b], acc[1][b], acc[2][b], acc[3][b]);
        p[1] = make_float4(acc[4][b], acc[5][b], acc[6][b], acc[7][b]);
    }
    __syncthreads();
    const float S = scrSum[0] + scrSum[1] + scrSum[2] + scrSum[3];

    // phase 2 GEMM: r[j,h] = sum_k P[j,k]*g2[k,h]; then z[h] = sum_j silu(v1[j,h])*r[j,h] / S
    const int h0  = (tid & 15) * 4;
    const int jj0 = (tid >> 4) * 8;
    float r[8][4];
#pragma unroll
    for (int a = 0; a < 8; a++)
#pragma unroll
        for (int b = 0; b < 4; b++) r[a][b] = 0.f;
#pragma unroll 4
    for (int k = 0; k < TT; k++) {
        float av[8], bv[4];
#pragma unroll
        for (int a = 0; a < 8; a++) av[a] = attnT[k][jj0 + a];
#pragma unroll
        for (int b = 0; b < 4; b++) bv[b] = shG2[k][h0 + b];
#pragma unroll
        for (int a = 0; a < 8; a++)
#pragma unroll
            for (int b = 0; b < 4; b++)
                r[a][b] = fmaf(av[a], bv[b], r[a][b]);
    }
    float zp[4] = {0.f, 0.f, 0.f, 0.f};
#pragma unroll
    for (int a = 0; a < 8; a++) {
        const float* v1r = v1 + (size_t)(bn*TT + jj0 + a)*DD + h0;
#pragma unroll
        for (int b = 0; b < 4; b++) {
            float x = __ldg(v1r + b);
            float g = x / (1.0f + __expf(-x));
            zp[b] += g * r[a][b];
        }
    }
    ((float4*)&shZ[tid >> 4][h0])[0] = make_float4(zp[0], zp[1], zp[2], zp[3]);
    __syncthreads();
    if (tid < DD) {
        float zs = 0.f;
#pragma unroll
        for (int t = 0; t < 16; t++) zs += shZ[t][tid];
        out[OFF_Z + (size_t)bid*DD + tid] = zs / S;
    }
    if (tid == 0) {
        out[OFF_M + (size_t)bid] = M;
        out[OFF_L + (size_t)bid] = S + 0.01f;
    }
}

extern "C" void kernel_launch(void* const* d_in, const int* in_sizes, int n_in,
                              void* d_out, int out_size, void* d_ws, size_t ws_size,
                              hipStream_t stream) {
    (void)in_sizes; (void)n_in; (void)d_ws; (void)ws_size; (void)out_size;
    const float* q  = (const float*)d_in[0];
    const float* k1 = (const float*)d_in[1];
    const float* k2 = (const float*)d_in[2];
    const float* v1 = (const float*)d_in[3];
    const float* v2 = (const float*)d_in[4];
    float* out = (float*)d_out;

    dim3 grid(BHN * TT);
    dim3 block(256);
    k_vg<<<grid, block, 0, stream>>>(v1, v2, out);
    k_score<<<grid, block, 0, stream>>>(q, k1, k2, out);
    k_z<<<grid, block, 0, stream>>>(q, k1, k2, v1, v2, out);
}

// Round 2
// 227.545 us; speedup vs baseline: 2.0620x; 2.0620x over previous
//
#include <hip/hip_runtime.h>

#define TT 128
#define DD 64
#define BHN 32
#define SCALE 0.125f
#define NEGF -1000000.0f

// float-element offsets into d_out (concatenated return order: z, pre, vg, M, L)
#define OFF_Z   ((size_t)0)
#define OFF_PRE ((size_t)(BHN*TT*DD))                       // 262144
#define OFF_VG  (OFF_PRE + (size_t)BHN*TT*TT*TT)            // 67371008
#define OFF_M   (OFF_VG + (size_t)BHN*TT*TT*DD)             // 100925440
#define OFF_L   (OFF_M + (size_t)(BHN*TT))                  // 100929536

typedef __attribute__((ext_vector_type(8))) short short8b;   // 8 bf16 (4 VGPRs)
typedef __attribute__((ext_vector_type(4))) short short4b;
typedef __attribute__((ext_vector_type(4))) float f32x4;

__device__ __forceinline__ short f2bf(float f) {
    union { float f; unsigned u; } v; v.f = f;
    unsigned r = v.u + 0x7FFFu + ((v.u >> 16) & 1u);   // RNE
    return (short)(r >> 16);
}

// ---------------- v_gated: vg[bn, p, t, h] = silu(v1[p,h]) * v2[t,h] ----------------
__global__ __launch_bounds__(256) void k_vg(const float* __restrict__ v1,
                                            const float* __restrict__ v2,
                                            float* __restrict__ out) {
    const int bid = blockIdx.x;      // bn*128 + p
    const int bn  = bid >> 7;
    const int p   = bid & 127;
    const int tid = threadIdx.x;
    __shared__ float g1[DD];
    if (tid < DD) {
        float x = v1[(size_t)(bn*TT + p)*DD + tid];
        g1[tid] = x / (1.0f + __expf(-x));
    }
    __syncthreads();
    const float4* v2f = (const float4*)(v2 + (size_t)bn*TT*DD);
    float4* dst = (float4*)(out + OFF_VG + (size_t)bid*TT*DD);
    const float4* g14 = (const float4*)g1;
    for (int i = tid; i < TT*DD/4; i += 256) {
        int h4 = i & 15;
        float4 v = v2f[i];
        float4 g = g14[h4];
        float4 r;
        r.x = v.x * g.x; r.y = v.y * g.y; r.z = v.z * g.z; r.w = v.w * g.w;
        dst[i] = r;
    }
}

// ---------------- pre_softmax: per (bn, j) block, s[k,q] = sum_h k1[j,h]*k2[k,h]*q[q,h] ----------------
__global__ __launch_bounds__(256) void k_score(const float* __restrict__ q,
                                               const float* __restrict__ k1,
                                               const float* __restrict__ k2,
                                               float* __restrict__ out) {
    const int bid = blockIdx.x;      // bn*128 + j
    const int bn  = bid >> 7;
    const int j   = bid & 127;
    const int tid = threadIdx.x;
    __shared__ float shW[DD][132];   // w[h][k] = k1[j,h]*k2[k,h]
    __shared__ float shQ[DD][132];   // q[h][qq]
    const float* k1r = k1 + (size_t)bid*DD;
    const float* k2t = k2 + (size_t)bn*TT*DD;
    const float* qt  = q  + (size_t)bn*TT*DD;
    for (int e = tid; e < TT*DD; e += 256) {
        int r = e >> 6;
        int h = e & 63;
        float k1v = __ldg(k1r + h);
        shW[h][r] = k1v * k2t[e];
        shQ[h][r] = qt[e];
    }
    __syncthreads();
    const int q0 = (tid & 15) * 8;
    const int k0 = (tid >> 4) * 8;
    float acc[8][8];
#pragma unroll
    for (int a = 0; a < 8; a++)
#pragma unroll
        for (int b = 0; b < 8; b++) acc[a][b] = 0.f;
#pragma unroll 4
    for (int h = 0; h < DD; h++) {
        float wv[8], qv[8];
#pragma unroll
        for (int a = 0; a < 8; a++) wv[a] = shW[h][k0 + a];
#pragma unroll
        for (int b = 0; b < 8; b++) qv[b] = shQ[h][q0 + b];
#pragma unroll
        for (int a = 0; a < 8; a++)
#pragma unroll
            for (int b = 0; b < 8; b++)
                acc[a][b] = fmaf(wv[a], qv[b], acc[a][b]);
    }
    float* dst = out + OFF_PRE + (size_t)bid*TT*TT;   // [k][q] tile, q innermost
#pragma unroll
    for (int a = 0; a < 8; a++) {
        const int k = k0 + a;
        float row[8];
#pragma unroll
        for (int b = 0; b < 8; b++) {
            int qi = q0 + b;
            row[b] = ((j <= qi) && (k <= qi)) ? acc[a][b] : NEGF;
        }
        float4* p = (float4*)(dst + (size_t)k*TT + q0);
        p[0] = make_float4(row[0], row[1], row[2], row[3]);
        p[1] = make_float4(row[4], row[5], row[6], row[7]);
    }
}

// ---------------- z, M, L: per (bn, q) block — MFMA bf16 version ----------------
__global__ __launch_bounds__(256) void k_z(const float* __restrict__ q,
                                           const float* __restrict__ k1,
                                           const float* __restrict__ k2,
                                           const float* __restrict__ v1,
                                           const float* __restrict__ v2,
                                           float* __restrict__ out) {
    const int bid = blockIdx.x;      // bn*128 + qq
    const int bn  = bid >> 7;
    const int qq  = bid & 127;
    const int tid = threadIdx.x;
    const int w    = tid >> 6;       // wave 0..3
    const int lane = tid & 63;
    const int lr   = lane & 15;
    const int lg   = lane >> 4;

    // phase1: A[128][64] bf16 + B[128][64] bf16 (each 16KB); phase2 union: P[128][128] bf16 (32KB)
    __shared__ short shAB[2 * TT * DD];
    __shared__ short shG2T[DD * TT];   // G2T[h=64][k=128] bf16 swizzled (16KB)
    __shared__ float zred[4][DD];
    __shared__ float scrMax[4];
    __shared__ float scrSum[4];

    short* shA = shAB;
    short* shB = shAB + TT * DD;
    short* shP = shAB;

    const float* qrow = q  + (size_t)bid * DD;
    const float* k1t  = k1 + (size_t)bn * TT * DD;
    const float* k2t  = k2 + (size_t)bn * TT * DD;
    const float* v1t  = v1 + (size_t)bn * TT * DD;
    const float* v2t  = v2 + (size_t)bn * TT * DD;

    // ---- stage A = k1 .* qv, B = k2, G2T = v2^T (all bf16, XOR-swizzled) ----
    {
        const int h0 = (tid * 4) & 63;                 // constant across iterations
        const float4 qv4 = *(const float4*)(qrow + h0);
#pragma unroll 4
        for (int e4 = tid; e4 < TT * DD / 4; e4 += 256) {
            const int e = e4 * 4;
            const int r = e >> 6;                      // row (j or k), 0..127
            const float4 a4 = *(const float4*)(k1t + e);
            const float4 b4 = *(const float4*)(k2t + e);
            const float4 g4 = *(const float4*)(v2t + e);
            short4b av, bv;
            av[0] = f2bf(a4.x * qv4.x); av[1] = f2bf(a4.y * qv4.y);
            av[2] = f2bf(a4.z * qv4.z); av[3] = f2bf(a4.w * qv4.w);
            bv[0] = f2bf(b4.x); bv[1] = f2bf(b4.y); bv[2] = f2bf(b4.z); bv[3] = f2bf(b4.w);
            const int idx = e ^ ((r & 7) << 3);        // short-index swizzle, keeps 4-short alignment
            *(short4b*)&shA[idx] = av;
            *(short4b*)&shB[idx] = bv;
            // G2T[h][k]: column writes (scalar b16)
            const int h = e & 63;
            shG2T[((h + 0) * TT + r) ^ (((h + 0) & 7) << 3)] = f2bf(g4.x);
            shG2T[((h + 1) * TT + r) ^ (((h + 1) & 7) << 3)] = f2bf(g4.y);
            shG2T[((h + 2) * TT + r) ^ (((h + 2) & 7) << 3)] = f2bf(g4.z);
            shG2T[((h + 3) * TT + r) ^ (((h + 3) & 7) << 3)] = f2bf(g4.w);
        }
    }
    __syncthreads();

    const int jbase = w * 32;        // wave's 32 j-rows

    // ---- phase 1: S[j,k] = sum_h A[j,h] * B[k,h]  (A-op M=j, B-op N=k, K=h=64) ----
    short8b af[2][2];
#pragma unroll
    for (int jt = 0; jt < 2; jt++)
#pragma unroll
        for (int ks = 0; ks < 2; ks++) {
            const int j  = jbase + jt * 16 + lr;
            const int hh = ks * 32 + lg * 8;
            af[jt][ks] = *(const short8b*)&shA[(j * DD + hh) ^ ((j & 7) << 3)];
        }

    f32x4 acc[2][8] = {};
#pragma unroll
    for (int kt = 0; kt < 8; kt++) {
        short8b bf[2];
#pragma unroll
        for (int ks = 0; ks < 2; ks++) {
            const int k  = kt * 16 + lr;
            const int hh = ks * 32 + lg * 8;
            bf[ks] = *(const short8b*)&shB[(k * DD + hh) ^ ((k & 7) << 3)];
        }
#pragma unroll
        for (int jt = 0; jt < 2; jt++)
#pragma unroll
            for (int ks = 0; ks < 2; ks++)
                acc[jt][kt] = __builtin_amdgcn_mfma_f32_16x16x32_bf16(af[jt][ks], bf[ks], acc[jt][kt], 0, 0, 0);
    }

    // ---- softmax: mask+scale, block max M, exp, sum S; P -> bf16 LDS ----
    float m = -3.4e38f;
#pragma unroll
    for (int jt = 0; jt < 2; jt++)
#pragma unroll
        for (int kt = 0; kt < 8; kt++)
#pragma unroll
            for (int r = 0; r < 4; r++) {
                const int j = jbase + jt * 16 + lg * 4 + r;    // C/D: row=(lane>>4)*4+reg
                const int k = kt * 16 + lr;                    //      col=lane&15
                float sv = ((j <= qq) && (k <= qq)) ? acc[jt][kt][r] * SCALE : (NEGF * SCALE);
                acc[jt][kt][r] = sv;
                m = fmaxf(m, sv);
            }
#pragma unroll
    for (int off = 32; off >= 1; off >>= 1) m = fmaxf(m, __shfl_xor(m, off));
    if (lane == 0) scrMax[w] = m;
    __syncthreads();                 // scrMax ready; phase-1 A/B reads complete
    const float M = fmaxf(fmaxf(scrMax[0], scrMax[1]), fmaxf(scrMax[2], scrMax[3]));

    float ssum = 0.f;
#pragma unroll
    for (int jt = 0; jt < 2; jt++)
#pragma unroll
        for (int kt = 0; kt < 8; kt++)
#pragma unroll
            for (int r = 0; r < 4; r++) {
                float p = __expf(acc[jt][kt][r] - M);   // masked -> exp(-125000-M) = 0, matches ref
                ssum += p;
                const int j = jbase + jt * 16 + lg * 4 + r;
                const int k = kt * 16 + lr;
                shP[(j * TT + k) ^ ((j & 7) << 3)] = f2bf(p);
            }
#pragma unroll
    for (int off = 32; off >= 1; off >>= 1) ssum += __shfl_xor(ssum, off);
    if (lane == 0) scrSum[w] = ssum;
    __syncthreads();                 // shP + scrSum + shG2T all visible
    const float S = scrSum[0] + scrSum[1] + scrSum[2] + scrSum[3];

    // ---- phase 2: R[j,h] = sum_k P[j,k] * G2[k,h]  (K=128) ----
    short8b pa[2][4];
#pragma unroll
    for (int jt = 0; jt < 2; jt++)
#pragma unroll
        for (int ks = 0; ks < 4; ks++) {
            const int j  = jbase + jt * 16 + lr;
            const int kk = ks * 32 + lg * 8;
            pa[jt][ks] = *(const short8b*)&shP[(j * TT + kk) ^ ((j & 7) << 3)];
        }

    f32x4 racc[2][4] = {};
#pragma unroll
    for (int ht = 0; ht < 4; ht++) {
#pragma unroll
        for (int ks = 0; ks < 4; ks++) {
            const int h  = ht * 16 + lr;
            const int kk = ks * 32 + lg * 8;
            short8b gb = *(const short8b*)&shG2T[(h * TT + kk) ^ ((h & 7) << 3)];
#pragma unroll
            for (int jt = 0; jt < 2; jt++)
                racc[jt][ht] = __builtin_amdgcn_mfma_f32_16x16x32_bf16(pa[jt][ks], gb, racc[jt][ht], 0, 0, 0);
        }
    }

    // ---- epilogue: z[h] = (1/S) * sum_j silu(v1[j,h]) * R[j,h] ----
    float zp[4] = {0.f, 0.f, 0.f, 0.f};
#pragma unroll
    for (int jt = 0; jt < 2; jt++)
#pragma unroll
        for (int ht = 0; ht < 4; ht++)
#pragma unroll
            for (int r = 0; r < 4; r++) {
                const int j = jbase + jt * 16 + lg * 4 + r;
                const int h = ht * 16 + lr;
                const float x = v1t[j * DD + h];
                const float g = x / (1.f + __expf(-x));
                zp[ht] += g * racc[jt][ht][r];
            }
#pragma unroll
    for (int ht = 0; ht < 4; ht++) {
        zp[ht] += __shfl_xor(zp[ht], 16);
        zp[ht] += __shfl_xor(zp[ht], 32);
    }
    if (lg == 0) {
#pragma unroll
        for (int ht = 0; ht < 4; ht++) zred[w][ht * 16 + lr] = zp[ht];
    }
    __syncthreads();
    if (tid < DD) {
        const float zs = zred[0][tid] + zred[1][tid] + zred[2][tid] + zred[3][tid];
        out[OFF_Z + (size_t)bid * DD + tid] = zs / S;
    }
    if (tid == 0) {
        out[OFF_M + (size_t)bid] = M;
        out[OFF_L + (size_t)bid] = S + 0.01f;
    }
}

extern "C" void kernel_launch(void* const* d_in, const int* in_sizes, int n_in,
                              void* d_out, int out_size, void* d_ws, size_t ws_size,
                              hipStream_t stream) {
    (void)in_sizes; (void)n_in; (void)d_ws; (void)ws_size; (void)out_size;
    const float* q  = (const float*)d_in[0];
    const float* k1 = (const float*)d_in[1];
    const float* k2 = (const float*)d_in[2];
    const float* v1 = (const float*)d_in[3];
    const float* v2 = (const float*)d_in[4];
    float* out = (float*)d_out;

    dim3 grid(BHN * TT);
    dim3 block(256);
    k_vg<<<grid, block, 0, stream>>>(v1, v2, out);
    k_score<<<grid, block, 0, stream>>>(q, k1, k2, out);
    k_z<<<grid, block, 0, stream>>>(q, k1, k2, v1, v2, out);
}

// Round 5
// 131.434 us; speedup vs baseline: 3.5698x; 1.7313x over previous
//
#include <hip/hip_runtime.h>

#define TT 128
#define DD 64
#define BHN 32
#define SCALE 0.125f
#define NEGF -1000000.0f

// float-element offsets into d_out (concatenated return order: z, pre, vg, M, L)
#define OFF_Z   ((size_t)0)
#define OFF_PRE ((size_t)(BHN*TT*DD))                       // 262144
#define OFF_VG  (OFF_PRE + (size_t)BHN*TT*TT*TT)            // 67371008
#define OFF_M   (OFF_VG + (size_t)BHN*TT*TT*DD)             // 100925440
#define OFF_L   (OFF_M + (size_t)(BHN*TT))                  // 100929536

typedef __attribute__((ext_vector_type(8))) short short8b;   // 8 bf16 (4 VGPRs)
typedef __attribute__((ext_vector_type(4))) short short4b;
typedef __attribute__((ext_vector_type(4))) float f32x4;

__device__ __forceinline__ short f2bf(float f) {
    union { float f; unsigned u; } v; v.f = f;
    unsigned r = v.u + 0x7FFFu + ((v.u >> 16) & 1u);   // RNE
    return (short)(r >> 16);
}

// ---- role bodies (inlined into the fused kernel; smem is the 50KB union) ----

__device__ __forceinline__ void do_vg(int sub, const float* __restrict__ v1,
                                      const float* __restrict__ v2,
                                      float* __restrict__ out, char* smem) {
    const int bn  = sub >> 7;
    const int p   = sub & 127;
    const int tid = threadIdx.x;
    float* g1 = (float*)smem;              // [64]
    if (tid < DD) {
        float x = v1[(size_t)(bn*TT + p)*DD + tid];
        g1[tid] = x / (1.0f + __expf(-x));
    }
    __syncthreads();
    const f32x4* v2f = (const f32x4*)(v2 + (size_t)bn*TT*DD);
    float* dst = out + OFF_VG + (size_t)sub*TT*DD;
    const f32x4* g14 = (const f32x4*)g1;
    for (int i = tid; i < TT*DD/4; i += 256) {
        int h4 = i & 15;
        f32x4 v = v2f[i];
        f32x4 g = g14[h4];
        f32x4 r = v * g;
        __builtin_nontemporal_store(r, (f32x4*)(dst) + i);
    }
}

// pre_softmax per (bn, j): S2[k,q] = sum_h (k1[j,h]*k2[k,h]) * q[q,h]  — bf16 MFMA
__device__ __forceinline__ void do_score(int sub, const float* __restrict__ q,
                                         const float* __restrict__ k1,
                                         const float* __restrict__ k2,
                                         float* __restrict__ out, char* smem) {
    const int bn  = sub >> 7;
    const int j   = sub & 127;
    const int tid = threadIdx.x;
    const int lane = tid & 63;
    const int w    = tid >> 6;
    const int lr   = lane & 15;
    const int lg   = lane >> 4;

    short* shW = (short*)smem;             // W[k][h] bf16 swizzled, 16KB
    short* shQ = (short*)smem + TT*DD;     // Q[q][h] bf16 swizzled, 16KB

    const float* k1r = k1 + (size_t)(bn*TT + j)*DD;
    const float* k2t = k2 + (size_t)bn*TT*DD;
    const float* qt  = q  + (size_t)bn*TT*DD;

    {
        const int h0 = (tid * 4) & 63;
        const f32x4 k1v = *(const f32x4*)(k1r + h0);
#pragma unroll 4
        for (int e4 = tid; e4 < TT*DD/4; e4 += 256) {
            const int e = e4 * 4;
            const int r = e >> 6;
            const f32x4 b4 = *(const f32x4*)(k2t + e);
            const f32x4 q4 = *(const f32x4*)(qt  + e);
            short4b wv, qv;
            wv[0] = f2bf(b4.x * k1v.x); wv[1] = f2bf(b4.y * k1v.y);
            wv[2] = f2bf(b4.z * k1v.z); wv[3] = f2bf(b4.w * k1v.w);
            qv[0] = f2bf(q4.x); qv[1] = f2bf(q4.y); qv[2] = f2bf(q4.z); qv[3] = f2bf(q4.w);
            const int idx = e ^ ((r & 7) << 3);
            *(short4b*)&shW[idx] = wv;
            *(short4b*)&shQ[idx] = qv;
        }
    }
    __syncthreads();

    const int kbase = w * 32;
    short8b wf[2][2];
#pragma unroll
    for (int mt = 0; mt < 2; mt++)
#pragma unroll
        for (int ks = 0; ks < 2; ks++) {
            const int k  = kbase + mt * 16 + lr;
            const int hh = ks * 32 + lg * 8;
            wf[mt][ks] = *(const short8b*)&shW[(k * DD + hh) ^ ((k & 7) << 3)];
        }
    f32x4 acc[2][8] = {};
#pragma unroll
    for (int qt8 = 0; qt8 < 8; qt8++) {
        short8b qf[2];
#pragma unroll
        for (int ks = 0; ks < 2; ks++) {
            const int qi = qt8 * 16 + lr;
            const int hh = ks * 32 + lg * 8;
            qf[ks] = *(const short8b*)&shQ[(qi * DD + hh) ^ ((qi & 7) << 3)];
        }
#pragma unroll
        for (int mt = 0; mt < 2; mt++)
#pragma unroll
            for (int ks = 0; ks < 2; ks++)
                acc[mt][qt8] = __builtin_amdgcn_mfma_f32_16x16x32_bf16(wf[mt][ks], qf[ks], acc[mt][qt8], 0, 0, 0);
    }

    float* dst = out + OFF_PRE + (size_t)sub*TT*TT;   // [k][q], q innermost
#pragma unroll
    for (int mt = 0; mt < 2; mt++)
#pragma unroll
        for (int qt8 = 0; qt8 < 8; qt8++)
#pragma unroll
            for (int r = 0; r < 4; r++) {
                const int k  = kbase + mt * 16 + lg * 4 + r;   // C/D row
                const int qi = qt8 * 16 + lr;                  // C/D col
                const float v = ((j <= qi) && (k <= qi)) ? acc[mt][qt8][r] : NEGF;
                __builtin_nontemporal_store(v, dst + (size_t)k * TT + qi);
            }
}

// z, M, L per (bn, q) — bf16 MFMA (round-2 verified)
__device__ __forceinline__ void do_z(int sub, const float* __restrict__ q,
                                     const float* __restrict__ k1,
                                     const float* __restrict__ k2,
                                     const float* __restrict__ v1,
                                     const float* __restrict__ v2,
                                     float* __restrict__ out, char* smem) {
    const int bn  = sub >> 7;
    const int qq  = sub & 127;
    const int tid = threadIdx.x;
    const int w    = tid >> 6;
    const int lane = tid & 63;
    const int lr   = lane & 15;
    const int lg   = lane >> 4;

    short* shAB  = (short*)smem;                    // 32KB: A[128][64]+B[128][64]; phase2: P[128][128]
    short* shG2T = (short*)(smem + 32768);          // 16KB: G2T[64][128]
    float* zred  = (float*)(smem + 49152);          // 4*64 floats = 1KB
    float* scrMax = (float*)(smem + 50176);         // 4
    float* scrSum = (float*)(smem + 50192);         // 4

    short* shA = shAB;
    short* shB = shAB + TT * DD;
    short* shP = shAB;

    const float* qrow = q  + (size_t)sub * DD;
    const float* k1t  = k1 + (size_t)bn * TT * DD;
    const float* k2t  = k2 + (size_t)bn * TT * DD;
    const float* v1t  = v1 + (size_t)bn * TT * DD;
    const float* v2t  = v2 + (size_t)bn * TT * DD;

    {
        const int h0 = (tid * 4) & 63;
        const f32x4 qv4 = *(const f32x4*)(qrow + h0);
#pragma unroll 4
        for (int e4 = tid; e4 < TT * DD / 4; e4 += 256) {
            const int e = e4 * 4;
            const int r = e >> 6;
            const f32x4 a4 = *(const f32x4*)(k1t + e);
            const f32x4 b4 = *(const f32x4*)(k2t + e);
            const f32x4 g4 = *(const f32x4*)(v2t + e);
            short4b av, bv;
            av[0] = f2bf(a4.x * qv4.x); av[1] = f2bf(a4.y * qv4.y);
            av[2] = f2bf(a4.z * qv4.z); av[3] = f2bf(a4.w * qv4.w);
            bv[0] = f2bf(b4.x); bv[1] = f2bf(b4.y); bv[2] = f2bf(b4.z); bv[3] = f2bf(b4.w);
            const int idx = e ^ ((r & 7) << 3);
            *(short4b*)&shA[idx] = av;
            *(short4b*)&shB[idx] = bv;
            const int h = e & 63;
            shG2T[((h + 0) * TT + r) ^ (((h + 0) & 7) << 3)] = f2bf(g4.x);
            shG2T[((h + 1) * TT + r) ^ (((h + 1) & 7) << 3)] = f2bf(g4.y);
            shG2T[((h + 2) * TT + r) ^ (((h + 2) & 7) << 3)] = f2bf(g4.z);
            shG2T[((h + 3) * TT + r) ^ (((h + 3) & 7) << 3)] = f2bf(g4.w);
        }
    }
    __syncthreads();

    const int jbase = w * 32;

    short8b af[2][2];
#pragma unroll
    for (int jt = 0; jt < 2; jt++)
#pragma unroll
        for (int ks = 0; ks < 2; ks++) {
            const int j  = jbase + jt * 16 + lr;
            const int hh = ks * 32 + lg * 8;
            af[jt][ks] = *(const short8b*)&shA[(j * DD + hh) ^ ((j & 7) << 3)];
        }
    f32x4 acc[2][8] = {};
#pragma unroll
    for (int kt = 0; kt < 8; kt++) {
        short8b bf[2];
#pragma unroll
        for (int ks = 0; ks < 2; ks++) {
            const int k  = kt * 16 + lr;
            const int hh = ks * 32 + lg * 8;
            bf[ks] = *(const short8b*)&shB[(k * DD + hh) ^ ((k & 7) << 3)];
        }
#pragma unroll
        for (int jt = 0; jt < 2; jt++)
#pragma unroll
            for (int ks = 0; ks < 2; ks++)
                acc[jt][kt] = __builtin_amdgcn_mfma_f32_16x16x32_bf16(af[jt][ks], bf[ks], acc[jt][kt], 0, 0, 0);
    }

    float m = -3.4e38f;
#pragma unroll
    for (int jt = 0; jt < 2; jt++)
#pragma unroll
        for (int kt = 0; kt < 8; kt++)
#pragma unroll
            for (int r = 0; r < 4; r++) {
                const int j = jbase + jt * 16 + lg * 4 + r;
                const int k = kt * 16 + lr;
                float sv = ((j <= qq) && (k <= qq)) ? acc[jt][kt][r] * SCALE : (NEGF * SCALE);
                acc[jt][kt][r] = sv;
                m = fmaxf(m, sv);
            }
#pragma unroll
    for (int off = 32; off >= 1; off >>= 1) m = fmaxf(m, __shfl_xor(m, off));
    if (lane == 0) scrMax[w] = m;
    __syncthreads();
    const float M = fmaxf(fmaxf(scrMax[0], scrMax[1]), fmaxf(scrMax[2], scrMax[3]));

    float ssum = 0.f;
#pragma unroll
    for (int jt = 0; jt < 2; jt++)
#pragma unroll
        for (int kt = 0; kt < 8; kt++)
#pragma unroll
            for (int r = 0; r < 4; r++) {
                float p = __expf(acc[jt][kt][r] - M);
                ssum += p;
                const int j = jbase + jt * 16 + lg * 4 + r;
                const int k = kt * 16 + lr;
                shP[(j * TT + k) ^ ((j & 7) << 3)] = f2bf(p);
            }
#pragma unroll
    for (int off = 32; off >= 1; off >>= 1) ssum += __shfl_xor(ssum, off);
    if (lane == 0) scrSum[w] = ssum;
    __syncthreads();
    const float S = scrSum[0] + scrSum[1] + scrSum[2] + scrSum[3];

    short8b pa[2][4];
#pragma unroll
    for (int jt = 0; jt < 2; jt++)
#pragma unroll
        for (int ks = 0; ks < 4; ks++) {
            const int j  = jbase + jt * 16 + lr;
            const int kk = ks * 32 + lg * 8;
            pa[jt][ks] = *(const short8b*)&shP[(j * TT + kk) ^ ((j & 7) << 3)];
        }
    f32x4 racc[2][4] = {};
#pragma unroll
    for (int ht = 0; ht < 4; ht++) {
#pragma unroll
        for (int ks = 0; ks < 4; ks++) {
            const int h  = ht * 16 + lr;
            const int kk = ks * 32 + lg * 8;
            short8b gb = *(const short8b*)&shG2T[(h * TT + kk) ^ ((h & 7) << 3)];
#pragma unroll
            for (int jt = 0; jt < 2; jt++)
                racc[jt][ht] = __builtin_amdgcn_mfma_f32_16x16x32_bf16(pa[jt][ks], gb, racc[jt][ht], 0, 0, 0);
        }
    }

    float zp[4] = {0.f, 0.f, 0.f, 0.f};
#pragma unroll
    for (int jt = 0; jt < 2; jt++)
#pragma unroll
        for (int ht = 0; ht < 4; ht++)
#pragma unroll
            for (int r = 0; r < 4; r++) {
                const int j = jbase + jt * 16 + lg * 4 + r;
                const int h = ht * 16 + lr;
                const float x = v1t[j * DD + h];
                const float g = x / (1.f + __expf(-x));
                zp[ht] += g * racc[jt][ht][r];
            }
#pragma unroll
    for (int ht = 0; ht < 4; ht++) {
        zp[ht] += __shfl_xor(zp[ht], 16);
        zp[ht] += __shfl_xor(zp[ht], 32);
    }
    if (lg == 0) {
#pragma unroll
        for (int ht = 0; ht < 4; ht++) zred[w * DD + ht * 16 + lr] = zp[ht];
    }
    __syncthreads();
    if (tid < DD) {
        const float zs = zred[0*DD + tid] + zred[1*DD + tid] + zred[2*DD + tid] + zred[3*DD + tid];
        out[OFF_Z + (size_t)sub * DD + tid] = zs / S;
    }
    if (tid == 0) {
        out[OFF_M + (size_t)sub] = M;
        out[OFF_L + (size_t)sub] = S + 0.01f;
    }
}

__global__ __launch_bounds__(256) void k_fused(const float* __restrict__ q,
                                               const float* __restrict__ k1,
                                               const float* __restrict__ k2,
                                               const float* __restrict__ v1,
                                               const float* __restrict__ v2,
                                               float* __restrict__ out) {
    __shared__ __align__(16) char smem[50240];
    const int bid  = blockIdx.x;
    const int role = bid % 3;           // 3 coprime with 8 XCDs -> uniform role spread
    const int sub  = bid / 3;           // 0..4095
    if (role == 0)      do_z(sub, q, k1, k2, v1, v2, out, smem);
    else if (role == 1) do_score(sub, q, k1, k2, out, smem);
    else                do_vg(sub, v1, v2, out, smem);
}

extern "C" void kernel_launch(void* const* d_in, const int* in_sizes, int n_in,
                              void* d_out, int out_size, void* d_ws, size_t ws_size,
                              hipStream_t stream) {
    (void)in_sizes; (void)n_in; (void)d_ws; (void)ws_size; (void)out_size;
    const float* q  = (const float*)d_in[0];
    const float* k1 = (const float*)d_in[1];
    const float* k2 = (const float*)d_in[2];
    const float* v1 = (const float*)d_in[3];
    const float* v2 = (const float*)d_in[4];
    float* out = (float*)d_out;

    k_fused<<<dim3(3 * BHN * TT), dim3(256), 0, stream>>>(q, k1, k2, v1, v2, out);
}